// Round 5
// baseline (109.825 us; speedup 1.0000x reference)
//
#include <hip/hip_runtime.h>
#include <hip/hip_bf16.h>
#include <math.h>

#define BB  8
#define HH  512
#define WW  512

#define TS 16
#define GT 18            // guidance tile with 1-px halo
#define GS 20            // g_pk row stride (u32)
#define FT 20            // flow tile with 2-px halo
#define FP 21            // f_lds row stride (f32)
#define HS 44            // h_s row stride (u32)
#define ZOFF (3*GT*GS)   // start of zero pad region in g_pk
#define ZPAD 320         // pad words: covers max gbase (15*GS+15 = 315)

#define NT 512           // threads per block (8 waves)
#define NW 8             // waves per block

typedef __attribute__((ext_vector_type(8))) short  short8;
typedef __attribute__((ext_vector_type(4))) float  float4v;
typedef __attribute__((ext_vector_type(4))) int    int4v;
typedef __attribute__((ext_vector_type(4))) uint   uint4v;

#define MFMA16(a,b,c) __builtin_amdgcn_mfma_f32_16x16x32_bf16((a),(b),(c),0,0,0)

// ---------- RNE split (setup only) ----------
static __device__ __forceinline__ ushort f2bf_rne(float f) {
    uint u = __float_as_uint(f);
    u += 0x7fffu + ((u >> 16) & 1u);
    return (ushort)(u >> 16);
}
static __device__ __forceinline__ void split_rne(float f, ushort& hi, ushort& lo) {
    hi = f2bf_rne(f);
    float r = f - __uint_as_float((uint)hi << 16);
    lo = f2bf_rne(r);
}
// ---------- truncation split, packed (hot path) ----------
static __device__ __forceinline__ uint pack_split(float f) {
    uint u  = __float_as_uint(f);
    uint hi = u & 0xFFFF0000u;
    float r = f - __uint_as_float(hi);          // exact residual
    return hi | (__float_as_uint(r) >> 16);
}

// ===================== setup: per-lane MFMA params -> ws =====================
// chunk layout (uint4 ws[chunk*64 + lane]):
//  0..1  a1h[t]   2..3  a1l[t]      (w1 as [32 oc][27 k] padded K=32)
//  4..7  a2h[mt]  8..11 a2l[mt]     (w2 channel-split, taps padded to 32)
// 12..13 acc1 bias init [t]
// 14..17 acc2 bias init [mt]
// 18..21 offv int4 [mt]             (patch gather offsets, f32 units)
// 22..23 off1 int4 [half]           (guidance gather offsets, u32 units)
__global__ __launch_bounds__(64)
void setup_params(const float* __restrict__ w1, const float* __restrict__ b1,
                  const float* __restrict__ w2, const float* __restrict__ b2,
                  uint4v* __restrict__ ws)
{
    const int L = threadIdx.x;
    const int c = L & 15, q = L >> 4;

    #pragma unroll
    for (int t = 0; t < 2; ++t) {
        short8 hi8, lo8;
        #pragma unroll
        for (int i = 0; i < 8; ++i) {
            const int k = 8 * q + i;
            const float f = (k < 27) ? w1[(16 * t + c) * 27 + k] : 0.f;
            ushort h_, l_; split_rne(f, h_, l_);
            hi8[i] = (short)h_; lo8[i] = (short)l_;
        }
        *reinterpret_cast<short8*>(&ws[(0 + t) * 64 + L]) = hi8;
        *reinterpret_cast<short8*>(&ws[(2 + t) * 64 + L]) = lo8;
    }
    #pragma unroll
    for (int mt = 0; mt < 4; ++mt) {
        const int ch = mt >> 1;
        const int kk = 16 * (mt & 1) + c;       // kernel tap of this A-row
        short8 hi8, lo8;
        #pragma unroll
        for (int i = 0; i < 8; ++i) {
            const float f = (kk < 25) ? w2[(25 * ch + kk) * 32 + 8 * q + i] : 0.f;
            ushort h_, l_; split_rne(f, h_, l_);
            hi8[i] = (short)h_; lo8[i] = (short)l_;
        }
        *reinterpret_cast<short8*>(&ws[(4 + mt) * 64 + L]) = hi8;
        *reinterpret_cast<short8*>(&ws[(8 + mt) * 64 + L]) = lo8;
    }
    #pragma unroll
    for (int t = 0; t < 2; ++t) {
        float4v v;
        #pragma unroll
        for (int r = 0; r < 4; ++r) v[r] = b1[16 * t + 4 * q + r];
        *reinterpret_cast<float4v*>(&ws[(12 + t) * 64 + L]) = v;
    }
    #pragma unroll
    for (int mt = 0; mt < 4; ++mt) {
        const int ch = mt >> 1;
        float4v v; int4v o;
        #pragma unroll
        for (int r = 0; r < 4; ++r) {
            const int kk = 16 * (mt & 1) + 4 * q + r;
            if (kk < 25) {
                v[r] = b2[25 * ch + kk];
                o[r] = ch * (FT * FP) + (kk / 5) * FP + (kk % 5);
            } else { v[r] = 0.f; o[r] = 0; }
        }
        *reinterpret_cast<float4v*>(&ws[(14 + mt) * 64 + L]) = v;
        *reinterpret_cast<int4v*>(&ws[(18 + mt) * 64 + L]) = o;
    }
    #pragma unroll
    for (int hf = 0; hf < 2; ++hf) {
        int4v o;
        #pragma unroll
        for (int i2 = 0; i2 < 4; ++i2) {
            const int k = 8 * q + 4 * hf + i2;
            if (k < 27) {
                const int ic = k / 9, r9 = k - ic * 9;
                o[i2] = ic * (GT * GS) + (r9 / 3) * GS + (r9 % 3);
            } else o[i2] = ZOFF;                // zero pad region (covers +gbase)
        }
        *reinterpret_cast<int4v*>(&ws[(22 + hf) * 64 + L]) = o;
    }
}

// ============================== main kernel ==============================
__global__ __launch_bounds__(NT, 4)
void temporal_refine_kernel(const float* __restrict__ v0,
                            const float* __restrict__ v2,
                            const uint4v* __restrict__ P,
                            float* __restrict__ out)
{
    __shared__ uint  g_pk[3 * GT * GS + ZPAD];  // packed (bf16hi<<16)|bf16lo
    __shared__ float f_lds[2 * FT * FP];
    __shared__ uint  h_s[NW * 16 * HS];         // per-wave packed h bounce

    const int bx0 = blockIdx.x * TS;
    const int by0 = blockIdx.y * TS;
    const int b   = blockIdx.z;
    const int tid = threadIdx.x;
    const int w   = tid >> 6;
    const int L   = tid & 63;
    const int c   = L & 15;
    const int q   = L >> 4;

    const float* v0b = v0 + (size_t)b * 2 * HH * WW;
    const float* v2b = v2 + (size_t)b * 2 * HH * WW;

    // ---- per-lane params (coalesced, L1/L2-resident) ----
    short8 a1h[2], a1l[2], a2h[4], a2l[4];
    #pragma unroll
    for (int t = 0; t < 2; ++t) {
        a1h[t] = *reinterpret_cast<const short8*>(&P[(0 + t) * 64 + L]);
        a1l[t] = *reinterpret_cast<const short8*>(&P[(2 + t) * 64 + L]);
    }
    #pragma unroll
    for (int mt = 0; mt < 4; ++mt) {
        a2h[mt] = *reinterpret_cast<const short8*>(&P[(4 + mt) * 64 + L]);
        a2l[mt] = *reinterpret_cast<const short8*>(&P[(8 + mt) * 64 + L]);
    }
    float4v bi1[2], bi2[4];
    #pragma unroll
    for (int t = 0; t < 2; ++t)
        bi1[t] = *reinterpret_cast<const float4v*>(&P[(12 + t) * 64 + L]);
    #pragma unroll
    for (int mt = 0; mt < 4; ++mt)
        bi2[mt] = *reinterpret_cast<const float4v*>(&P[(14 + mt) * 64 + L]);
    int offv[16], off1[8];
    #pragma unroll
    for (int mt = 0; mt < 4; ++mt) {
        const int4v o = *reinterpret_cast<const int4v*>(&P[(18 + mt) * 64 + L]);
        #pragma unroll
        for (int r = 0; r < 4; ++r) offv[mt * 4 + r] = o[r];
    }
    #pragma unroll
    for (int hf = 0; hf < 2; ++hf) {
        const int4v o = *reinterpret_cast<const int4v*>(&P[(22 + hf) * 64 + L]);
        #pragma unroll
        for (int i2 = 0; i2 < 4; ++i2) off1[hf * 4 + i2] = o[i2];
    }

    // ---- stage flow tile (halo 2), single shot ----
    if (tid < FT * FT) {
        const int ly = tid / FT, lx = tid - (tid / FT) * FT;
        const int y = by0 - 2 + ly, x = bx0 - 2 + lx;
        float f0 = 0.f, f1 = 0.f;
        if (y >= 0 && y < HH && x >= 0 && x < WW) {
            f0 = v0b[y * WW + x];
            f1 = v0b[HH * WW + y * WW + x];
        }
        f_lds[0 * FT * FP + ly * FP + lx] = f0;
        f_lds[1 * FT * FP + ly * FP + lx] = f1;
    }
    // zero pad region for conv1-K padding reads
    if (tid < ZPAD) g_pk[ZOFF + tid] = 0u;
    __syncthreads();

    // ---- stage guidance tile (halo 1), single shot; v0 from LDS ----
    if (tid < GT * GT) {
        const int ly = tid / GT, lx = tid - (tid / GT) * GT;
        const int y = by0 - 1 + ly, x = bx0 - 1 + lx;
        float fb0 = 0.f, fb1 = 0.f, wv = 0.f;
        if (y >= 0 && y < HH && x >= 0 && x < WW) {
            const float f0 = f_lds[0 * FT * FP + (ly + 1) * FP + (lx + 1)];
            const float f1 = f_lds[1 * FT * FP + (ly + 1) * FP + (lx + 1)];
            const float sgx = (-1.0f + x * (2.0f / (WW - 1))) + f0 * (2.0f / WW);
            const float sgy = (-1.0f + y * (2.0f / (HH - 1))) + f1 * (2.0f / HH);
            const float ixf = (sgx + 1.0f) * (0.5f * (WW - 1));
            const float iyf = (sgy + 1.0f) * (0.5f * (HH - 1));
            const float x0f = floorf(ixf), y0f = floorf(iyf);
            const int   x0  = (int)x0f,   y0i = (int)y0f;
            const float wx1 = ixf - x0f, wx0 = 1.0f - wx1;
            const float wy1 = iyf - y0f, wy0 = 1.0f - wy1;
            float s0 = 0.f, s1 = 0.f;
            #pragma unroll
            for (int cy = 0; cy < 2; ++cy) {
                const int yy = y0i + cy;
                const float wy = cy ? wy1 : wy0;
                if (yy >= 0 && yy < HH) {
                    #pragma unroll
                    for (int cx = 0; cx < 2; ++cx) {
                        const int xx = x0 + cx;
                        if (xx >= 0 && xx < WW) {
                            const float wgt = wy * (cx ? wx1 : wx0);
                            const int idx = yy * WW + xx;
                            s0 = fmaf(wgt, v2b[idx], s0);
                            s1 = fmaf(wgt, v2b[HH * WW + idx], s1);
                        }
                    }
                }
            }
            fb0 = f0 + s0;
            fb1 = f1 + s1;
            wv  = __expf(-sqrtf(fmaf(fb0, fb0, fb1 * fb1)));
        }
        g_pk[0 * GT * GS + ly * GS + lx] = pack_split(fb0);
        g_pk[1 * GT * GS + ly * GS + lx] = pack_split(fb1);
        g_pk[2 * GT * GS + ly * GS + lx] = pack_split(wv);
    }
    __syncthreads();

    uint* hw = h_s + w * (16 * HS);

    // ---- 2 groups of 16 pixels per wave ----
    #pragma unroll
    for (int g = 0; g < 2; ++g) {
        const int py = 2 * w + g;
        const int gbase = py * GS + c;

        // B1 frag: 8 packed gathers + unpack
        uint u[8];
        #pragma unroll
        for (int i = 0; i < 8; ++i) u[i] = g_pk[off1[i] + gbase];
        short8 b1h, b1l;
        #pragma unroll
        for (int i = 0; i < 8; ++i) {
            b1h[i] = (short)(u[i] >> 16);
            b1l[i] = (short)(u[i] & 0xFFFFu);
        }

        // conv3x3 GEMM, bias pre-loaded in C
        float4v acc1[2] = {bi1[0], bi1[1]};
        #pragma unroll
        for (int t = 0; t < 2; ++t) {
            acc1[t] = MFMA16(a1h[t], b1h, acc1[t]);
            acc1[t] = MFMA16(a1h[t], b1l, acc1[t]);
            acc1[t] = MFMA16(a1l[t], b1h, acc1[t]);
        }

        // ReLU + packed split -> LDS bounce (C-layout -> B-layout)
        #pragma unroll
        for (int t = 0; t < 2; ++t) {
            uint4v pk;
            #pragma unroll
            for (int r = 0; r < 4; ++r)
                pk[r] = pack_split(fmaxf(acc1[t][r], 0.f));
            *reinterpret_cast<uint4v*>(&hw[c * HS + 16 * t + 4 * q]) = pk;
        }
        const uint4v r0 = *reinterpret_cast<const uint4v*>(&hw[c * HS + 8 * q]);
        const uint4v r1 = *reinterpret_cast<const uint4v*>(&hw[c * HS + 8 * q + 4]);
        short8 b2h, b2l;
        #pragma unroll
        for (int i = 0; i < 4; ++i) {
            b2h[i]     = (short)(r0[i] >> 16);
            b2l[i]     = (short)(r0[i] & 0xFFFFu);
            b2h[4 + i] = (short)(r1[i] >> 16);
            b2l[4 + i] = (short)(r1[i] & 0xFFFFu);
        }

        // conv1x1 GEMM, bias pre-loaded in C
        float4v acc2[4] = {bi2[0], bi2[1], bi2[2], bi2[3]};
        #pragma unroll
        for (int mt = 0; mt < 4; ++mt) {
            acc2[mt] = MFMA16(a2h[mt], b2h, acc2[mt]);
            acc2[mt] = MFMA16(a2h[mt], b2l, acc2[mt]);
            acc2[mt] = MFMA16(a2l[mt], b2h, acc2[mt]);
        }

        // combine: kern includes bias; dead taps have kern == 0
        const float* fbase = f_lds + py * FP + c;
        float s0 = 0.f, s1 = 0.f;
        #pragma unroll
        for (int j = 0; j < 16; ++j) {
            const float patch = fbase[offv[j]];
            const float kern  = acc2[j >> 2][j & 3];
            if (j < 8) s0 = fmaf(kern, patch, s0);
            else       s1 = fmaf(kern, patch, s1);
        }
        s0 += __shfl_xor(s0, 16);
        s0 += __shfl_xor(s0, 32);
        s1 += __shfl_xor(s1, 16);
        s1 += __shfl_xor(s1, 32);

        if (q == 0) {
            const int y = by0 + py, x = bx0 + c;
            out[((size_t)b * 2 + 0) * HH * WW + y * WW + x] = s0;
            out[((size_t)b * 2 + 1) * HH * WW + y * WW + x] = s1;
        }
    }
}

extern "C" void kernel_launch(void* const* d_in, const int* in_sizes, int n_in,
                              void* d_out, int out_size, void* d_ws, size_t ws_size,
                              hipStream_t stream) {
    const float* v0 = (const float*)d_in[0];
    const float* v2 = (const float*)d_in[1];
    const float* w1 = (const float*)d_in[2];
    const float* b1 = (const float*)d_in[3];
    const float* w2 = (const float*)d_in[4];
    const float* b2 = (const float*)d_in[5];
    uint4v* ws = (uint4v*)d_ws;

    setup_params<<<1, 64, 0, stream>>>(w1, b1, w2, b2, ws);

    dim3 grid(WW / TS, HH / TS, BB);
    temporal_refine_kernel<<<grid, dim3(NT, 1, 1), 0, stream>>>(v0, v2, ws, (float*)d_out);
}

// Round 6
// 94.337 us; speedup vs baseline: 1.1642x; 1.1642x over previous
//
#include <hip/hip_runtime.h>
#include <hip/hip_bf16.h>
#include <math.h>

#define BB  8
#define HH  512
#define WW  512
#define HW  (HH*WW)

#define TS 16
#define GT 18            // guidance tile with 1-px halo
#define GS 20            // g_pk row stride (u32)
#define FT 20            // flow tile with 2-px halo
#define FP 21            // f_lds row stride (f32)
#define HS 44            // h_s row stride (u32)
#define ZOFF (3*GT*GS)   // start of zero pad region in g_pk
#define ZPAD 320         // covers max gbase (15*GS+15 = 315)

#define WS_GOFF 32768    // guidance buffer offset in d_ws (params live below)
#define WS_NEED (WS_GOFF + (size_t)BB*3*HW*4)

typedef __attribute__((ext_vector_type(8))) short  short8;
typedef __attribute__((ext_vector_type(4))) float  float4v;
typedef __attribute__((ext_vector_type(4))) int    int4v;
typedef __attribute__((ext_vector_type(4))) uint   uint4v;

#define MFMA16(a,b,c) __builtin_amdgcn_mfma_f32_16x16x32_bf16((a),(b),(c),0,0,0)

// ---------- RNE split (setup only) ----------
static __device__ __forceinline__ ushort f2bf_rne(float f) {
    uint u = __float_as_uint(f);
    u += 0x7fffu + ((u >> 16) & 1u);
    return (ushort)(u >> 16);
}
static __device__ __forceinline__ void split_rne(float f, ushort& hi, ushort& lo) {
    hi = f2bf_rne(f);
    float r = f - __uint_as_float((uint)hi << 16);
    lo = f2bf_rne(r);
}
// ---------- truncation split, packed (hot path) ----------
static __device__ __forceinline__ uint pack_split(float f) {
    uint u  = __float_as_uint(f);
    uint hi = u & 0xFFFF0000u;
    float r = f - __uint_as_float(hi);          // exact residual
    return hi | (__float_as_uint(r) >> 16);
}

// ---------- shared guidance math ----------
static __device__ __forceinline__ void guidance_at(
    const float* __restrict__ v2b, int x, int y, float f0, float f1,
    float& fb0, float& fb1, float& wv)
{
    const float sgx = (-1.0f + x * (2.0f / (WW - 1))) + f0 * (2.0f / WW);
    const float sgy = (-1.0f + y * (2.0f / (HH - 1))) + f1 * (2.0f / HH);
    const float ixf = (sgx + 1.0f) * (0.5f * (WW - 1));
    const float iyf = (sgy + 1.0f) * (0.5f * (HH - 1));
    const float x0f = floorf(ixf), y0f = floorf(iyf);
    const int   x0  = (int)x0f,   y0i = (int)y0f;
    const float wx1 = ixf - x0f, wx0 = 1.0f - wx1;
    const float wy1 = iyf - y0f, wy0 = 1.0f - wy1;
    float s0 = 0.f, s1 = 0.f;
    #pragma unroll
    for (int cy = 0; cy < 2; ++cy) {
        const int yy = y0i + cy;
        const float wy = cy ? wy1 : wy0;
        if (yy >= 0 && yy < HH) {
            #pragma unroll
            for (int cx = 0; cx < 2; ++cx) {
                const int xx = x0 + cx;
                if (xx >= 0 && xx < WW) {
                    const float wgt = wy * (cx ? wx1 : wx0);
                    const int idx = yy * WW + xx;
                    s0 = fmaf(wgt, v2b[idx], s0);
                    s1 = fmaf(wgt, v2b[HW + idx], s1);
                }
            }
        }
    }
    fb0 = f0 + s0;
    fb1 = f1 + s1;
    wv  = __expf(-sqrtf(fmaf(fb0, fb0, fb1 * fb1)));
}

// ===================== setup: per-lane MFMA params -> ws =====================
__global__ __launch_bounds__(64)
void setup_params(const float* __restrict__ w1, const float* __restrict__ b1,
                  const float* __restrict__ w2, const float* __restrict__ b2,
                  uint4v* __restrict__ ws)
{
    const int L = threadIdx.x;
    const int c = L & 15, q = L >> 4;

    #pragma unroll
    for (int t = 0; t < 2; ++t) {
        short8 hi8, lo8;
        #pragma unroll
        for (int i = 0; i < 8; ++i) {
            const int k = 8 * q + i;
            const float f = (k < 27) ? w1[(16 * t + c) * 27 + k] : 0.f;
            ushort h_, l_; split_rne(f, h_, l_);
            hi8[i] = (short)h_; lo8[i] = (short)l_;
        }
        *reinterpret_cast<short8*>(&ws[(0 + t) * 64 + L]) = hi8;
        *reinterpret_cast<short8*>(&ws[(2 + t) * 64 + L]) = lo8;
    }
    #pragma unroll
    for (int mt = 0; mt < 4; ++mt) {
        const int ch = mt >> 1;
        const int kk = 16 * (mt & 1) + c;
        short8 hi8, lo8;
        #pragma unroll
        for (int i = 0; i < 8; ++i) {
            const float f = (kk < 25) ? w2[(25 * ch + kk) * 32 + 8 * q + i] : 0.f;
            ushort h_, l_; split_rne(f, h_, l_);
            hi8[i] = (short)h_; lo8[i] = (short)l_;
        }
        *reinterpret_cast<short8*>(&ws[(4 + mt) * 64 + L]) = hi8;
        *reinterpret_cast<short8*>(&ws[(8 + mt) * 64 + L]) = lo8;
    }
    #pragma unroll
    for (int t = 0; t < 2; ++t) {
        float4v v;
        #pragma unroll
        for (int r = 0; r < 4; ++r) v[r] = b1[16 * t + 4 * q + r];
        *reinterpret_cast<float4v*>(&ws[(12 + t) * 64 + L]) = v;
    }
    #pragma unroll
    for (int mt = 0; mt < 4; ++mt) {
        const int ch = mt >> 1;
        float4v v; int4v o;
        #pragma unroll
        for (int r = 0; r < 4; ++r) {
            const int kk = 16 * (mt & 1) + 4 * q + r;
            if (kk < 25) {
                v[r] = b2[25 * ch + kk];
                o[r] = ch * (FT * FP) + (kk / 5) * FP + (kk % 5);
            } else { v[r] = 0.f; o[r] = 0; }
        }
        *reinterpret_cast<float4v*>(&ws[(14 + mt) * 64 + L]) = v;
        *reinterpret_cast<int4v*>(&ws[(18 + mt) * 64 + L]) = o;
    }
    #pragma unroll
    for (int hf = 0; hf < 2; ++hf) {
        int4v o;
        #pragma unroll
        for (int i2 = 0; i2 < 4; ++i2) {
            const int k = 8 * q + 4 * hf + i2;
            if (k < 27) {
                const int ic = k / 9, r9 = k - ic * 9;
                o[i2] = ic * (GT * GS) + (r9 / 3) * GS + (r9 % 3);
            } else o[i2] = ZOFF;
        }
        *reinterpret_cast<int4v*>(&ws[(22 + hf) * 64 + L]) = o;
    }
}

// ================== K1: guidance field (streaming, no LDS) ==================
__global__ __launch_bounds__(256)
void guidance_kernel(const float* __restrict__ v0,
                     const float* __restrict__ v2,
                     uint* __restrict__ G)
{
    const int idx = blockIdx.x * 256 + threadIdx.x;   // [B*H*W]
    const int x = idx & (WW - 1);
    const int y = (idx >> 9) & (HH - 1);
    const int b = idx >> 18;

    const float* v0b = v0 + (size_t)b * 2 * HW;
    const float* v2b = v2 + (size_t)b * 2 * HW;

    const float f0 = v0b[y * WW + x];
    const float f1 = v0b[HW + y * WW + x];
    float fb0, fb1, wv;
    guidance_at(v2b, x, y, f0, f1, fb0, fb1, wv);

    const size_t base = (size_t)b * 3 * HW + y * WW + x;
    G[base]          = pack_split(fb0);
    G[base + HW]     = pack_split(fb1);
    G[base + 2 * HW] = pack_split(wv);
}

// =============== K2: convs + combine (reads packed guidance) ===============
__global__ __launch_bounds__(256, 2)
void refine_kernel(const float* __restrict__ v0,
                   const uint* __restrict__ G,
                   const uint4v* __restrict__ P,
                   float* __restrict__ out)
{
    __shared__ uint  g_pk[3 * GT * GS + ZPAD];
    __shared__ float f_lds[2 * FT * FP];
    __shared__ uint  h_s[4 * 16 * HS];

    const int bx0 = blockIdx.x * TS;
    const int by0 = blockIdx.y * TS;
    const int b   = blockIdx.z;
    const int tid = threadIdx.x;
    const int w   = tid >> 6;
    const int L   = tid & 63;
    const int c   = L & 15;
    const int q   = L >> 4;

    const float* v0b = v0 + (size_t)b * 2 * HW;
    const uint*  Gb  = G + (size_t)b * 3 * HW;

    // ---- per-lane params (L1-resident, loaded once) ----
    short8 a1h[2], a1l[2], a2h[4], a2l[4];
    #pragma unroll
    for (int t = 0; t < 2; ++t) {
        a1h[t] = *reinterpret_cast<const short8*>(&P[(0 + t) * 64 + L]);
        a1l[t] = *reinterpret_cast<const short8*>(&P[(2 + t) * 64 + L]);
    }
    #pragma unroll
    for (int mt = 0; mt < 4; ++mt) {
        a2h[mt] = *reinterpret_cast<const short8*>(&P[(4 + mt) * 64 + L]);
        a2l[mt] = *reinterpret_cast<const short8*>(&P[(8 + mt) * 64 + L]);
    }
    float4v bi1[2], bi2[4];
    #pragma unroll
    for (int t = 0; t < 2; ++t)
        bi1[t] = *reinterpret_cast<const float4v*>(&P[(12 + t) * 64 + L]);
    #pragma unroll
    for (int mt = 0; mt < 4; ++mt)
        bi2[mt] = *reinterpret_cast<const float4v*>(&P[(14 + mt) * 64 + L]);
    int offv[16], off1[8];
    #pragma unroll
    for (int mt = 0; mt < 4; ++mt) {
        const int4v o = *reinterpret_cast<const int4v*>(&P[(18 + mt) * 64 + L]);
        #pragma unroll
        for (int r = 0; r < 4; ++r) offv[mt * 4 + r] = o[r];
    }
    #pragma unroll
    for (int hf = 0; hf < 2; ++hf) {
        const int4v o = *reinterpret_cast<const int4v*>(&P[(22 + hf) * 64 + L]);
        #pragma unroll
        for (int i2 = 0; i2 < 4; ++i2) off1[hf * 4 + i2] = o[i2];
    }

    // ---- stage flow tile (halo 2): coalesced, no dependent gather ----
    #pragma unroll
    for (int i = tid; i < FT * FT; i += 256) {
        const int ly = i / FT, lx = i - (i / FT) * FT;
        const int y = by0 - 2 + ly, x = bx0 - 2 + lx;
        float f0 = 0.f, f1 = 0.f;
        if (y >= 0 && y < HH && x >= 0 && x < WW) {
            f0 = v0b[y * WW + x];
            f1 = v0b[HW + y * WW + x];
        }
        f_lds[0 * FT * FP + ly * FP + lx] = f0;
        f_lds[1 * FT * FP + ly * FP + lx] = f1;
    }
    // ---- stage packed guidance tile (halo 1): coalesced ----
    #pragma unroll
    for (int i = tid; i < GT * GT; i += 256) {
        const int ly = i / GT, lx = i - (i / GT) * GT;
        const int y = by0 - 1 + ly, x = bx0 - 1 + lx;
        uint u0 = 0u, u1 = 0u, u2 = 0u;
        if (y >= 0 && y < HH && x >= 0 && x < WW) {
            const size_t base = (size_t)y * WW + x;
            u0 = Gb[base];
            u1 = Gb[base + HW];
            u2 = Gb[base + 2 * HW];
        }
        g_pk[0 * GT * GS + ly * GS + lx] = u0;
        g_pk[1 * GT * GS + ly * GS + lx] = u1;
        g_pk[2 * GT * GS + ly * GS + lx] = u2;
    }
    // zero pad region for conv1-K padding reads
    #pragma unroll
    for (int i = tid; i < ZPAD; i += 256) g_pk[ZOFF + i] = 0u;
    __syncthreads();

    uint* hw = h_s + w * (16 * HS);

    // ---- 4 groups of 16 pixels per wave ----
    #pragma unroll
    for (int g = 0; g < 4; ++g) {
        const int py = w * 4 + g;
        const int gbase = py * GS + c;

        // B1 frag: 8 packed gathers + unpack
        uint u[8];
        #pragma unroll
        for (int i = 0; i < 8; ++i) u[i] = g_pk[off1[i] + gbase];
        short8 b1h, b1l;
        #pragma unroll
        for (int i = 0; i < 8; ++i) {
            b1h[i] = (short)(u[i] >> 16);
            b1l[i] = (short)(u[i] & 0xFFFFu);
        }

        // conv3x3 GEMM, bias pre-loaded in C
        float4v acc1[2] = {bi1[0], bi1[1]};
        #pragma unroll
        for (int t = 0; t < 2; ++t) {
            acc1[t] = MFMA16(a1h[t], b1h, acc1[t]);
            acc1[t] = MFMA16(a1h[t], b1l, acc1[t]);
            acc1[t] = MFMA16(a1l[t], b1h, acc1[t]);
        }

        // ReLU + packed split -> LDS bounce (C-layout -> B-layout)
        #pragma unroll
        for (int t = 0; t < 2; ++t) {
            uint4v pk;
            #pragma unroll
            for (int r = 0; r < 4; ++r)
                pk[r] = pack_split(fmaxf(acc1[t][r], 0.f));
            *reinterpret_cast<uint4v*>(&hw[c * HS + 16 * t + 4 * q]) = pk;
        }
        const uint4v r0 = *reinterpret_cast<const uint4v*>(&hw[c * HS + 8 * q]);
        const uint4v r1 = *reinterpret_cast<const uint4v*>(&hw[c * HS + 8 * q + 4]);
        short8 b2h, b2l;
        #pragma unroll
        for (int i = 0; i < 4; ++i) {
            b2h[i]     = (short)(r0[i] >> 16);
            b2l[i]     = (short)(r0[i] & 0xFFFFu);
            b2h[4 + i] = (short)(r1[i] >> 16);
            b2l[4 + i] = (short)(r1[i] & 0xFFFFu);
        }

        // conv1x1 GEMM, bias pre-loaded in C
        float4v acc2[4] = {bi2[0], bi2[1], bi2[2], bi2[3]};
        #pragma unroll
        for (int mt = 0; mt < 4; ++mt) {
            acc2[mt] = MFMA16(a2h[mt], b2h, acc2[mt]);
            acc2[mt] = MFMA16(a2h[mt], b2l, acc2[mt]);
            acc2[mt] = MFMA16(a2l[mt], b2h, acc2[mt]);
        }

        // combine
        const float* fbase = f_lds + py * FP + c;
        float s0 = 0.f, s1 = 0.f;
        #pragma unroll
        for (int j = 0; j < 16; ++j) {
            const float patch = fbase[offv[j]];
            const float kern  = acc2[j >> 2][j & 3];
            if (j < 8) s0 = fmaf(kern, patch, s0);
            else       s1 = fmaf(kern, patch, s1);
        }
        s0 += __shfl_xor(s0, 16);
        s0 += __shfl_xor(s0, 32);
        s1 += __shfl_xor(s1, 16);
        s1 += __shfl_xor(s1, 32);

        if (q == 0) {
            const int y = by0 + py, x = bx0 + c;
            out[((size_t)b * 2 + 0) * HW + y * WW + x] = s0;
            out[((size_t)b * 2 + 1) * HW + y * WW + x] = s1;
        }
    }
}

// ================= fallback: fused (round-4 structure) =================
__global__ __launch_bounds__(256)
void fused_kernel(const float* __restrict__ v0,
                  const float* __restrict__ v2,
                  const uint4v* __restrict__ P,
                  float* __restrict__ out)
{
    __shared__ uint  g_pk[3 * GT * GS + ZPAD];
    __shared__ float f_lds[2 * FT * FP];
    __shared__ uint  h_s[4 * 16 * HS];

    const int bx0 = blockIdx.x * TS;
    const int by0 = blockIdx.y * TS;
    const int b   = blockIdx.z;
    const int tid = threadIdx.x;
    const int w   = tid >> 6;
    const int L   = tid & 63;
    const int c   = L & 15;
    const int q   = L >> 4;

    const float* v0b = v0 + (size_t)b * 2 * HW;
    const float* v2b = v2 + (size_t)b * 2 * HW;

    short8 a1h[2], a1l[2], a2h[4], a2l[4];
    #pragma unroll
    for (int t = 0; t < 2; ++t) {
        a1h[t] = *reinterpret_cast<const short8*>(&P[(0 + t) * 64 + L]);
        a1l[t] = *reinterpret_cast<const short8*>(&P[(2 + t) * 64 + L]);
    }
    #pragma unroll
    for (int mt = 0; mt < 4; ++mt) {
        a2h[mt] = *reinterpret_cast<const short8*>(&P[(4 + mt) * 64 + L]);
        a2l[mt] = *reinterpret_cast<const short8*>(&P[(8 + mt) * 64 + L]);
    }
    float4v bi1[2], bi2[4];
    #pragma unroll
    for (int t = 0; t < 2; ++t)
        bi1[t] = *reinterpret_cast<const float4v*>(&P[(12 + t) * 64 + L]);
    #pragma unroll
    for (int mt = 0; mt < 4; ++mt)
        bi2[mt] = *reinterpret_cast<const float4v*>(&P[(14 + mt) * 64 + L]);
    int offv[16], off1[8];
    #pragma unroll
    for (int mt = 0; mt < 4; ++mt) {
        const int4v o = *reinterpret_cast<const int4v*>(&P[(18 + mt) * 64 + L]);
        #pragma unroll
        for (int r = 0; r < 4; ++r) offv[mt * 4 + r] = o[r];
    }
    #pragma unroll
    for (int hf = 0; hf < 2; ++hf) {
        const int4v o = *reinterpret_cast<const int4v*>(&P[(22 + hf) * 64 + L]);
        #pragma unroll
        for (int i2 = 0; i2 < 4; ++i2) off1[hf * 4 + i2] = o[i2];
    }

    for (int i = tid; i < GT * GT; i += 256) {
        const int ly = i / GT, lx = i - (i / GT) * GT;
        const int y = by0 - 1 + ly, x = bx0 - 1 + lx;
        float fb0 = 0.f, fb1 = 0.f, wv = 0.f;
        if (y >= 0 && y < HH && x >= 0 && x < WW) {
            const float f0 = v0b[y * WW + x];
            const float f1 = v0b[HW + y * WW + x];
            guidance_at(v2b, x, y, f0, f1, fb0, fb1, wv);
        }
        g_pk[0 * GT * GS + ly * GS + lx] = pack_split(fb0);
        g_pk[1 * GT * GS + ly * GS + lx] = pack_split(fb1);
        g_pk[2 * GT * GS + ly * GS + lx] = pack_split(wv);
    }
    for (int i = tid; i < ZPAD; i += 256) g_pk[ZOFF + i] = 0u;
    for (int i = tid; i < FT * FT; i += 256) {
        const int ly = i / FT, lx = i - (i / FT) * FT;
        const int y = by0 - 2 + ly, x = bx0 - 2 + lx;
        float f0 = 0.f, f1 = 0.f;
        if (y >= 0 && y < HH && x >= 0 && x < WW) {
            f0 = v0b[y * WW + x];
            f1 = v0b[HW + y * WW + x];
        }
        f_lds[0 * FT * FP + ly * FP + lx] = f0;
        f_lds[1 * FT * FP + ly * FP + lx] = f1;
    }
    __syncthreads();

    uint* hw = h_s + w * (16 * HS);

    #pragma unroll
    for (int g = 0; g < 4; ++g) {
        const int py = w * 4 + g;
        const int gbase = py * GS + c;
        uint u[8];
        #pragma unroll
        for (int i = 0; i < 8; ++i) u[i] = g_pk[off1[i] + gbase];
        short8 b1h, b1l;
        #pragma unroll
        for (int i = 0; i < 8; ++i) {
            b1h[i] = (short)(u[i] >> 16);
            b1l[i] = (short)(u[i] & 0xFFFFu);
        }
        float4v acc1[2] = {bi1[0], bi1[1]};
        #pragma unroll
        for (int t = 0; t < 2; ++t) {
            acc1[t] = MFMA16(a1h[t], b1h, acc1[t]);
            acc1[t] = MFMA16(a1h[t], b1l, acc1[t]);
            acc1[t] = MFMA16(a1l[t], b1h, acc1[t]);
        }
        #pragma unroll
        for (int t = 0; t < 2; ++t) {
            uint4v pk;
            #pragma unroll
            for (int r = 0; r < 4; ++r)
                pk[r] = pack_split(fmaxf(acc1[t][r], 0.f));
            *reinterpret_cast<uint4v*>(&hw[c * HS + 16 * t + 4 * q]) = pk;
        }
        const uint4v r0 = *reinterpret_cast<const uint4v*>(&hw[c * HS + 8 * q]);
        const uint4v r1 = *reinterpret_cast<const uint4v*>(&hw[c * HS + 8 * q + 4]);
        short8 b2h, b2l;
        #pragma unroll
        for (int i = 0; i < 4; ++i) {
            b2h[i]     = (short)(r0[i] >> 16);
            b2l[i]     = (short)(r0[i] & 0xFFFFu);
            b2h[4 + i] = (short)(r1[i] >> 16);
            b2l[4 + i] = (short)(r1[i] & 0xFFFFu);
        }
        float4v acc2[4] = {bi2[0], bi2[1], bi2[2], bi2[3]};
        #pragma unroll
        for (int mt = 0; mt < 4; ++mt) {
            acc2[mt] = MFMA16(a2h[mt], b2h, acc2[mt]);
            acc2[mt] = MFMA16(a2h[mt], b2l, acc2[mt]);
            acc2[mt] = MFMA16(a2l[mt], b2h, acc2[mt]);
        }
        const float* fbase = f_lds + py * FP + c;
        float s0 = 0.f, s1 = 0.f;
        #pragma unroll
        for (int j = 0; j < 16; ++j) {
            const float patch = fbase[offv[j]];
            const float kern  = acc2[j >> 2][j & 3];
            if (j < 8) s0 = fmaf(kern, patch, s0);
            else       s1 = fmaf(kern, patch, s1);
        }
        s0 += __shfl_xor(s0, 16);
        s0 += __shfl_xor(s0, 32);
        s1 += __shfl_xor(s1, 16);
        s1 += __shfl_xor(s1, 32);
        if (q == 0) {
            const int y = by0 + py, x = bx0 + c;
            out[((size_t)b * 2 + 0) * HW + y * WW + x] = s0;
            out[((size_t)b * 2 + 1) * HW + y * WW + x] = s1;
        }
    }
}

extern "C" void kernel_launch(void* const* d_in, const int* in_sizes, int n_in,
                              void* d_out, int out_size, void* d_ws, size_t ws_size,
                              hipStream_t stream) {
    const float* v0 = (const float*)d_in[0];
    const float* v2 = (const float*)d_in[1];
    const float* w1 = (const float*)d_in[2];
    const float* b1 = (const float*)d_in[3];
    const float* w2 = (const float*)d_in[4];
    const float* b2 = (const float*)d_in[5];
    uint4v* ws = (uint4v*)d_ws;

    setup_params<<<1, 64, 0, stream>>>(w1, b1, w2, b2, ws);

    dim3 grid(WW / TS, HH / TS, BB);
    if (ws_size >= WS_NEED) {
        uint* G = (uint*)((char*)d_ws + WS_GOFF);
        guidance_kernel<<<(BB * HW) / 256, 256, 0, stream>>>(v0, v2, G);
        refine_kernel<<<grid, dim3(256, 1, 1), 0, stream>>>(v0, G, ws, (float*)d_out);
    } else {
        fused_kernel<<<grid, dim3(256, 1, 1), 0, stream>>>(v0, v2, ws, (float*)d_out);
    }
}

// Round 7
// 76.942 us; speedup vs baseline: 1.4274x; 1.2261x over previous
//
#include <hip/hip_runtime.h>
#include <math.h>

#define BB  8
#define HH  512
#define WW  512
#define HW  (HH*WW)

#define TSX 32           // tile width
#define TSY 32           // tile height
#define GR  34           // guidance tile rows/cols (halo 1)
#define GSS 36           // g_sh row stride (u16)
#define GPLANE (GR*GSS)  // 1224
#define FR  36           // flow tile rows/cols (halo 2)
#define FPS 37           // f_lds row stride (f32)
#define FPLANE (FR*FPS)  // 1332
#define HS  44           // h bounce row stride (u32)

#define WS_GOFF 32768    // G buffer offset in d_ws

typedef __attribute__((ext_vector_type(8))) short  short8;
typedef __attribute__((ext_vector_type(4))) float  float4v;
typedef __attribute__((ext_vector_type(4))) int    int4v;
typedef __attribute__((ext_vector_type(4))) uint   uint4v;

#define MFMA16(a,b,c) __builtin_amdgcn_mfma_f32_16x16x32_bf16((a),(b),(c),0,0,0)

// ---------- RNE bf16 ----------
static __device__ __forceinline__ ushort f2bf_rne(float f) {
    uint u = __float_as_uint(f);
    u += 0x7fffu + ((u >> 16) & 1u);
    return (ushort)(u >> 16);
}
static __device__ __forceinline__ void split_rne(float f, ushort& hi, ushort& lo) {
    hi = f2bf_rne(f);
    float r = f - __uint_as_float((uint)hi << 16);
    lo = f2bf_rne(r);
}
// ---------- truncation split, packed (h hot path) ----------
static __device__ __forceinline__ uint pack_split(float f) {
    uint u  = __float_as_uint(f);
    uint hi = u & 0xFFFF0000u;
    float r = f - __uint_as_float(hi);          // exact residual
    return hi | (__float_as_uint(r) >> 16);
}

// tap index for conv2 output row position (qr, rr) within a channel.
// Row-permuted so combine offsets are compile-time per (mt,r):
//  mt even: taps (ky=qr, kx=rr)         kk = 5*qr+rr
//  mt odd : rr=0 -> (qr,4)  kk=5*qr+4
//           rr=1 -> (4,qr)  kk=20+qr
//           rr=2 -> (4,4) only for qr==3, kk=24
//           else  invalid (zero row)
static __device__ __host__ __forceinline__ int tap_kk(int mtodd, int qr, int rr) {
    if (!mtodd) return 5 * qr + rr;
    if (rr == 0) return 5 * qr + 4;
    if (rr == 1) return 20 + qr;
    if (rr == 2 && qr == 3) return 24;
    return -1;
}

// ===================== setup: per-lane MFMA params -> ws =====================
// chunks (uint4 ws[chunk*64 + lane]):
//  0..1 a1h[t]  2..3 a1l[t]   (w1 [32 oc][27->32 k], split hi/lo)
//  4..7 a2h[mt] 8..11 a2l[mt] (w2 row-permuted per tap_kk, split hi/lo)
// 12..13 bi1[t]                (b1 at C-layout rows)
// 14..17 bi2[mt]               (b2 row-permuted, or 0)
// 18..19 off1 int4 [half]      (guidance gather offsets, u16 units; pad->0)
__global__ __launch_bounds__(64)
void setup_params(const float* __restrict__ w1, const float* __restrict__ b1,
                  const float* __restrict__ w2, const float* __restrict__ b2,
                  uint4v* __restrict__ ws)
{
    const int L = threadIdx.x;
    const int c = L & 15, q = L >> 4;

    #pragma unroll
    for (int t = 0; t < 2; ++t) {
        short8 hi8, lo8;
        #pragma unroll
        for (int i = 0; i < 8; ++i) {
            const int k = 8 * q + i;
            const float f = (k < 27) ? w1[(16 * t + c) * 27 + k] : 0.f;
            ushort h_, l_; split_rne(f, h_, l_);
            hi8[i] = (short)h_; lo8[i] = (short)l_;
        }
        *reinterpret_cast<short8*>(&ws[(0 + t) * 64 + L]) = hi8;
        *reinterpret_cast<short8*>(&ws[(2 + t) * 64 + L]) = lo8;
    }
    #pragma unroll
    for (int mt = 0; mt < 4; ++mt) {
        const int ch = mt >> 1;
        const int kk = tap_kk(mt & 1, c >> 2, c & 3);   // A-frag row = 16mt + c
        short8 hi8, lo8;
        #pragma unroll
        for (int i = 0; i < 8; ++i) {
            const float f = (kk >= 0) ? w2[(25 * ch + kk) * 32 + 8 * q + i] : 0.f;
            ushort h_, l_; split_rne(f, h_, l_);
            hi8[i] = (short)h_; lo8[i] = (short)l_;
        }
        *reinterpret_cast<short8*>(&ws[(4 + mt) * 64 + L]) = hi8;
        *reinterpret_cast<short8*>(&ws[(8 + mt) * 64 + L]) = lo8;
    }
    #pragma unroll
    for (int t = 0; t < 2; ++t) {
        float4v v;
        #pragma unroll
        for (int r = 0; r < 4; ++r) v[r] = b1[16 * t + 4 * q + r];
        *reinterpret_cast<float4v*>(&ws[(12 + t) * 64 + L]) = v;
    }
    #pragma unroll
    for (int mt = 0; mt < 4; ++mt) {
        const int ch = mt >> 1;
        float4v v;
        #pragma unroll
        for (int r = 0; r < 4; ++r) {
            const int kk = tap_kk(mt & 1, q, r);        // C-layout row = 16mt+4q+r
            v[r] = (kk >= 0) ? b2[25 * ch + kk] : 0.f;
        }
        *reinterpret_cast<float4v*>(&ws[(14 + mt) * 64 + L]) = v;
    }
    #pragma unroll
    for (int hf = 0; hf < 2; ++hf) {
        int4v o;
        #pragma unroll
        for (int i2 = 0; i2 < 4; ++i2) {
            const int k = 8 * q + 4 * hf + i2;
            if (k < 27) {
                const int ic = k / 9, r9 = k - ic * 9;
                o[i2] = ic * GPLANE + (r9 / 3) * GSS + (r9 % 3);
            } else o[i2] = 0;   // garbage read ok: A weight column is zero
        }
        *reinterpret_cast<int4v*>(&ws[(18 + hf) * 64 + L]) = o;
    }
}

// ================== K1: guidance field -> bf16 planes ==================
__global__ __launch_bounds__(256)
void guidance_kernel(const float* __restrict__ v0,
                     const float* __restrict__ v2,
                     ushort* __restrict__ G)
{
    const int idx = blockIdx.x * 256 + threadIdx.x;
    const int x = idx & (WW - 1);
    const int y = (idx >> 9) & (HH - 1);
    const int b = idx >> 18;

    const float* v0b = v0 + (size_t)b * 2 * HW;
    const float* v2b = v2 + (size_t)b * 2 * HW;

    const float f0 = v0b[y * WW + x];
    const float f1 = v0b[HW + y * WW + x];

    const float sgx = (-1.0f + x * (2.0f / (WW - 1))) + f0 * (2.0f / WW);
    const float sgy = (-1.0f + y * (2.0f / (HH - 1))) + f1 * (2.0f / HH);
    const float ixf = (sgx + 1.0f) * (0.5f * (WW - 1));
    const float iyf = (sgy + 1.0f) * (0.5f * (HH - 1));
    const float x0f = floorf(ixf), y0f = floorf(iyf);
    const int   x0  = (int)x0f,   y0i = (int)y0f;
    const float wx1 = ixf - x0f, wx0 = 1.0f - wx1;
    const float wy1 = iyf - y0f, wy0 = 1.0f - wy1;
    float s0 = 0.f, s1 = 0.f;
    #pragma unroll
    for (int cy = 0; cy < 2; ++cy) {
        const int yy = y0i + cy;
        const float wy = cy ? wy1 : wy0;
        if (yy >= 0 && yy < HH) {
            #pragma unroll
            for (int cx = 0; cx < 2; ++cx) {
                const int xx = x0 + cx;
                if (xx >= 0 && xx < WW) {
                    const float wgt = wy * (cx ? wx1 : wx0);
                    const int i2 = yy * WW + xx;
                    s0 = fmaf(wgt, v2b[i2], s0);
                    s1 = fmaf(wgt, v2b[HW + i2], s1);
                }
            }
        }
    }
    const float fb0 = f0 + s0;
    const float fb1 = f1 + s1;
    const float wv  = __expf(-sqrtf(fmaf(fb0, fb0, fb1 * fb1)));

    const size_t base = (size_t)b * 3 * HW + y * WW + x;
    G[base]          = f2bf_rne(fb0);
    G[base + HW]     = f2bf_rne(fb1);
    G[base + 2 * HW] = f2bf_rne(wv);
}

// =============== K2: convs + combine, 32x32 tile ===============
__global__ __launch_bounds__(256, 3)
void refine_kernel(const float* __restrict__ v0,
                   const ushort* __restrict__ G,
                   const uint4v* __restrict__ P,
                   float* __restrict__ out)
{
    __shared__ ushort g_sh[3 * GPLANE];           // bf16 guidance tile
    __shared__ float  f_lds[2 * FPLANE];          // flow tile (halo 2)
    __shared__ uint   h_s[4 * 2 * 16 * HS];       // per-wave double-buffered bounce

    const int bx0 = blockIdx.x * TSX;
    const int by0 = blockIdx.y * TSY;
    const int b   = blockIdx.z;
    const int tid = threadIdx.x;
    const int w   = tid >> 6;
    const int L   = tid & 63;
    const int c   = L & 15;
    const int q   = L >> 4;

    const float*  v0b = v0 + (size_t)b * 2 * HW;
    const ushort* Gb  = G + (size_t)b * 3 * HW;

    // ---- per-lane params ----
    short8 a1h[2], a1l[2], a2h[4], a2l[4];
    #pragma unroll
    for (int t = 0; t < 2; ++t) {
        a1h[t] = *reinterpret_cast<const short8*>(&P[(0 + t) * 64 + L]);
        a1l[t] = *reinterpret_cast<const short8*>(&P[(2 + t) * 64 + L]);
    }
    #pragma unroll
    for (int mt = 0; mt < 4; ++mt) {
        a2h[mt] = *reinterpret_cast<const short8*>(&P[(4 + mt) * 64 + L]);
        a2l[mt] = *reinterpret_cast<const short8*>(&P[(8 + mt) * 64 + L]);
    }
    float4v bi1[2], bi2[4];
    #pragma unroll
    for (int t = 0; t < 2; ++t)
        bi1[t] = *reinterpret_cast<const float4v*>(&P[(12 + t) * 64 + L]);
    #pragma unroll
    for (int mt = 0; mt < 4; ++mt)
        bi2[mt] = *reinterpret_cast<const float4v*>(&P[(14 + mt) * 64 + L]);
    int off1[8];
    #pragma unroll
    for (int hf = 0; hf < 2; ++hf) {
        const int4v o = *reinterpret_cast<const int4v*>(&P[(18 + hf) * 64 + L]);
        #pragma unroll
        for (int i2 = 0; i2 < 4; ++i2) off1[hf * 4 + i2] = o[i2];
    }

    // ---- stage flow tile (36x36, halo 2) ----
    for (int i = tid; i < FR * FR; i += 256) {
        const int ly = i / FR, lx = i - (i / FR) * FR;
        const int y = by0 - 2 + ly, x = bx0 - 2 + lx;
        float f0 = 0.f, f1 = 0.f;
        if ((unsigned)y < HH && (unsigned)x < WW) {
            f0 = v0b[y * WW + x];
            f1 = v0b[HW + y * WW + x];
        }
        f_lds[ly * FPS + lx]          = f0;
        f_lds[FPLANE + ly * FPS + lx] = f1;
    }
    // ---- stage guidance tile (34x34, halo 1), 3 bf16 planes ----
    for (int i = tid; i < GR * GR; i += 256) {
        const int ly = i / GR, lx = i - (i / GR) * GR;
        const int y = by0 - 1 + ly, x = bx0 - 1 + lx;
        ushort u0 = 0, u1 = 0, u2 = 0;
        if ((unsigned)y < HH && (unsigned)x < WW) {
            const size_t gi = (size_t)y * WW + x;
            u0 = Gb[gi];
            u1 = Gb[gi + HW];
            u2 = Gb[gi + 2 * HW];
        }
        g_sh[ly * GSS + lx]              = u0;
        g_sh[GPLANE + ly * GSS + lx]     = u1;
        g_sh[2 * GPLANE + ly * GSS + lx] = u2;
    }
    __syncthreads();

    uint* hw = h_s + w * (2 * 16 * HS);

    // ---- 16 groups of 16 px per wave: rows 8w..8w+7, halves 0/1 ----
    #pragma unroll 2
    for (int g = 0; g < 16; ++g) {
        const int py = 8 * w + (g >> 1);
        const int px = 16 * (g & 1) + c;
        const int gb = py * GSS + px;

        // B1 frag: 8 bf16 gathers (pad slots read garbage; A cols are zero)
        short8 b1;
        #pragma unroll
        for (int i = 0; i < 8; ++i) b1[i] = (short)g_sh[off1[i] + gb];

        // conv3x3 GEMM (bf16 B, split A), bias in C
        float4v acc1[2] = {bi1[0], bi1[1]};
        #pragma unroll
        for (int t = 0; t < 2; ++t) {
            acc1[t] = MFMA16(a1l[t], b1, acc1[t]);
            acc1[t] = MFMA16(a1h[t], b1, acc1[t]);
        }

        // ReLU + packed split -> LDS bounce (C-layout -> B-layout)
        uint* hb = hw + (g & 1) * (16 * HS);
        #pragma unroll
        for (int t = 0; t < 2; ++t) {
            uint4v pk;
            #pragma unroll
            for (int r = 0; r < 4; ++r)
                pk[r] = pack_split(fmaxf(acc1[t][r], 0.f));
            *reinterpret_cast<uint4v*>(&hb[c * HS + 16 * t + 4 * q]) = pk;
        }
        const uint4v r0 = *reinterpret_cast<const uint4v*>(&hb[c * HS + 8 * q]);
        const uint4v r1 = *reinterpret_cast<const uint4v*>(&hb[c * HS + 8 * q + 4]);
        short8 b2h, b2l;
        #pragma unroll
        for (int i = 0; i < 4; ++i) {
            b2h[i]     = (short)(r0[i] >> 16);
            b2l[i]     = (short)(r0[i] & 0xFFFFu);
            b2h[4 + i] = (short)(r1[i] >> 16);
            b2l[4 + i] = (short)(r1[i] & 0xFFFFu);
        }

        // conv1x1 GEMM (split 3-term), bias in C
        float4v acc2[4] = {bi2[0], bi2[1], bi2[2], bi2[3]};
        #pragma unroll
        for (int mt = 0; mt < 4; ++mt) {
            acc2[mt] = MFMA16(a2h[mt], b2h, acc2[mt]);
            acc2[mt] = MFMA16(a2h[mt], b2l, acc2[mt]);
            acc2[mt] = MFMA16(a2l[mt], b2h, acc2[mt]);
        }

        // combine: compile-time tap offsets (row-permuted conv2 output)
        const int pyb   = py * FPS + px;
        const int base0 = pyb + q * FPS;          // tap (q, 0..4)
        const int b4    = pyb + 4 * FPS + q;      // tap (4, q)
        const int base1 = base0 + FPLANE;
        const int b41   = b4 + FPLANE;

        float s0 = 0.f, s1 = 0.f;
        s0 = fmaf(acc2[0][0], f_lds[base0],      s0);
        s0 = fmaf(acc2[0][1], f_lds[base0 + 1],  s0);
        s0 = fmaf(acc2[0][2], f_lds[base0 + 2],  s0);
        s0 = fmaf(acc2[0][3], f_lds[base0 + 3],  s0);
        s0 = fmaf(acc2[1][0], f_lds[base0 + 4],  s0);
        s0 = fmaf(acc2[1][1], f_lds[b4],         s0);
        s0 = fmaf(acc2[1][2], f_lds[base0 + 41], s0);   // (4,4): kern==0 unless q==3
        s1 = fmaf(acc2[2][0], f_lds[base1],      s1);
        s1 = fmaf(acc2[2][1], f_lds[base1 + 1],  s1);
        s1 = fmaf(acc2[2][2], f_lds[base1 + 2],  s1);
        s1 = fmaf(acc2[2][3], f_lds[base1 + 3],  s1);
        s1 = fmaf(acc2[3][0], f_lds[base1 + 4],  s1);
        s1 = fmaf(acc2[3][1], f_lds[b41],        s1);
        s1 = fmaf(acc2[3][2], f_lds[base1 + 41], s1);

        s0 += __shfl_xor(s0, 16);
        s0 += __shfl_xor(s0, 32);
        s1 += __shfl_xor(s1, 16);
        s1 += __shfl_xor(s1, 32);

        if (q == 0) {
            const int y = by0 + py, x = bx0 + px;
            out[((size_t)b * 2 + 0) * HW + y * WW + x] = s0;
            out[((size_t)b * 2 + 1) * HW + y * WW + x] = s1;
        }
    }
}

extern "C" void kernel_launch(void* const* d_in, const int* in_sizes, int n_in,
                              void* d_out, int out_size, void* d_ws, size_t ws_size,
                              hipStream_t stream) {
    const float* v0 = (const float*)d_in[0];
    const float* v2 = (const float*)d_in[1];
    const float* w1 = (const float*)d_in[2];
    const float* b1 = (const float*)d_in[3];
    const float* w2 = (const float*)d_in[4];
    const float* b2 = (const float*)d_in[5];
    uint4v* ws = (uint4v*)d_ws;
    ushort* G  = (ushort*)((char*)d_ws + WS_GOFF);

    setup_params<<<1, 64, 0, stream>>>(w1, b1, w2, b2, ws);
    guidance_kernel<<<(BB * HW) / 256, 256, 0, stream>>>(v0, v2, G);

    dim3 grid(WW / TSX, HH / TSY, BB);
    refine_kernel<<<grid, dim3(256, 1, 1), 0, stream>>>(v0, G, ws, (float*)d_out);
}